// Round 6
// baseline (164.639 us; speedup 1.0000x reference)
//
#include <hip/hip_runtime.h>
#include <hip/hip_bf16.h>
#include <math.h>

#define Bb 8
#define Tt 512
#define Cc 512
#define Hh 8
#define HKV 4
#define Dd 64

typedef __attribute__((ext_vector_type(8))) short short8;
typedef __attribute__((ext_vector_type(4))) float float4v;
typedef __attribute__((ext_vector_type(2))) __fp16 h2;   // matches cvt_pkrtz return
typedef __attribute__((ext_vector_type(8))) __fp16 half8; // f16 MFMA fragment

__device__ __forceinline__ h2 u2h(unsigned u) {
  union { unsigned u; h2 h; } x; x.u = u; return x.h;
}
__device__ __forceinline__ unsigned h2u(h2 h) {
  union { h2 h; unsigned u; } x; x.h = h; return x.u;
}
__device__ __forceinline__ float fdot2(h2 a, h2 b, float c) {
#if __has_builtin(__builtin_amdgcn_fdot2)
  return __builtin_amdgcn_fdot2(a, b, c, false);
#else
  return fmaf((float)a.x, (float)b.x, fmaf((float)a.y, (float)b.y, c));
#endif
}

__device__ __forceinline__ float wave_reduce_sum(float v) {
#pragma unroll
  for (int off = 32; off > 0; off >>= 1) v += __shfl_xor(v, off, 64);
  return v;
}
__device__ __forceinline__ unsigned pack_bf2(float a, float b) {
  __hip_bfloat162 h = __float22bfloat162_rn(make_float2(a, b));
  return *(unsigned*)&h;
}

// v14 attn chunk table: (yp | jts<<8 | njt<<16), ordered by descending work so the
// x-fastest dispatch runs heavy chunks first (v13 lesson: order IS the schedule).
// yp = i0/32; tiles yp>=8 are split into two j-chunks (fixed-shift softmax => partials add).
__constant__ unsigned ATAB[24] = {
  0x04000F, 0x04000E, 0x04040F, 0x04040E, 0x04000D, 0x04000C,  // njt4 chunks
  0x03040D, 0x03040C, 0x03000B, 0x03000A, 0x03030B, 0x03030A,  // njt3 chunks
  0x030009, 0x030008,                                           // njt3 chunks
  0x040007, 0x040006,                                           // unsplit nt4
  0x020309, 0x020308,                                           // njt2 tails
  0x030005, 0x030004,                                           // unsplit nt3
  0x020003, 0x020002,                                           // unsplit nt2
  0x010001, 0x010000                                            // unsplit nt1
};

// ---------------- fused prep: conv_x | conv_w | build_pw (by block range) ----------------
__global__ __launch_bounds__(256) void prep(
    const float* __restrict__ x, const float* __restrict__ Wq,
    const float* __restrict__ Wk, const float* __restrict__ Wv,
    const float* __restrict__ Wp, const float* __restrict__ P,
    const float* __restrict__ sigma,
    unsigned short* __restrict__ xb, unsigned short* __restrict__ Wtq,
    unsigned short* __restrict__ Wtp, unsigned short* __restrict__ Pwh) {
  const int bid = blockIdx.x;
  const int t = threadIdx.x;
  if (bid < 1024) {
    int i = (bid * 256 + t) * 8;
    float4 f0 = *(const float4*)&x[i];
    float4 f1 = *(const float4*)&x[i + 4];
    unsigned u[4] = {pack_bf2(f0.x, f0.y), pack_bf2(f0.z, f0.w),
                     pack_bf2(f1.x, f1.y), pack_bf2(f1.z, f1.w)};
    *(uint4*)&xb[i] = *(uint4*)u;
  } else if (bid < 1216) {
    __shared__ float Ts[64][65];
    const int bx = bid - 1024;
    const int k0 = (bx & 7) << 6;
    const int n0 = (bx >> 3) << 6;
    const float* src; int ld, nc0; unsigned short* dst; int ndst;
    if (n0 < 512)       { src = Wq; ld = 512; nc0 = n0;        dst = Wtq; ndst = n0; }
    else if (n0 < 768)  { src = Wk; ld = 256; nc0 = n0 - 512;  dst = Wtq; ndst = n0; }
    else if (n0 < 1024) { src = Wv; ld = 256; nc0 = n0 - 768;  dst = Wtq; ndst = n0; }
    else                { src = Wp; ld = 512; nc0 = n0 - 1024; dst = Wtp; ndst = n0 - 1024; }
    const int r = t >> 4, c4 = (t & 15) << 2;
#pragma unroll
    for (int rr = 0; rr < 4; ++rr) {
      int row = (rr << 4) + r;
      float4 f = *(const float4*)&src[(k0 + row) * ld + nc0 + c4];
      Ts[row][c4] = f.x; Ts[row][c4 + 1] = f.y;
      Ts[row][c4 + 2] = f.z; Ts[row][c4 + 3] = f.w;
    }
    __syncthreads();
#pragma unroll
    for (int rr = 0; rr < 4; ++rr) {
      int nr = (rr << 4) + r;
      unsigned u0 = pack_bf2(Ts[c4][nr], Ts[c4 + 1][nr]);
      unsigned u1 = pack_bf2(Ts[c4 + 2][nr], Ts[c4 + 3][nr]);
      *(uint2*)&dst[(ndst + nr) * 512 + k0 + c4] = make_uint2(u0, u1);
    }
  } else {
    int idx = (bid - 1216) * 256 + t;
    int d = idx & 63;
    int rem = idx >> 6;
    int dd = rem % 1023;
    int h = rem / 1023;
    float s = fabsf(sigma[h]) + 1e-6f;
    float delta = (float)(dd - 511);
    float dt = 128.0f * tanhf(delta / s) + 128.0f;
    float lo = floorf(dt);
    int ilo = (int)lo;
    float frac = dt - lo;
    ilo = max(0, min(ilo, 256));
    int ihi = min(ilo + 1, 256);
    const float* Pb = P + h * 257 * 64;
    float val = (1.0f - frac) * Pb[ilo * 64 + d] + frac * Pb[ihi * 64 + d];
    __fp16 hv = (__fp16)val;
    Pwh[idx] = *(unsigned short*)&hv;
  }
}

// ---------------- QKV MFMA GEMM: 64x64 tile, padded LDS; v emitted TRANSPOSED ----------------
// sm_scale (1/8) folded into the q store -> attn drops its per-score multiply.
__global__ __launch_bounds__(256) void qkv_mfma(
    const unsigned short* __restrict__ xb, const unsigned short* __restrict__ Wt,
    unsigned short* __restrict__ qh, unsigned short* __restrict__ kh,
    unsigned short* __restrict__ vT) {
  __shared__ unsigned short As[64][72];
  __shared__ unsigned short Bs[64][72];
  const int m0 = blockIdx.x * 64;
  const int n0 = blockIdx.y * 64;
  const int t = threadIdx.x;
  const int w = t >> 6, lane = t & 63;
  const int srow = t >> 2, sc = (t & 3) << 4;
  float4v acc[4] = {{0,0,0,0},{0,0,0,0},{0,0,0,0},{0,0,0,0}};
  for (int k0 = 0; k0 < 512; k0 += 64) {
    uint4 a0 = *(const uint4*)&xb[(m0 + srow) * 512 + k0 + sc];
    uint4 a1 = *(const uint4*)&xb[(m0 + srow) * 512 + k0 + sc + 8];
    uint4 b0 = *(const uint4*)&Wt[(n0 + srow) * 512 + k0 + sc];
    uint4 b1 = *(const uint4*)&Wt[(n0 + srow) * 512 + k0 + sc + 8];
    __syncthreads();
    *(uint4*)&As[srow][sc] = a0; *(uint4*)&As[srow][sc + 8] = a1;
    *(uint4*)&Bs[srow][sc] = b0; *(uint4*)&Bs[srow][sc + 8] = b1;
    __syncthreads();
    const int ml = (w << 4) + (lane & 15);
    const int kq = (lane >> 4) << 3;
    short8 aF0 = *(short8*)&As[ml][kq];
    short8 aF1 = *(short8*)&As[ml][kq + 32];
#pragma unroll
    for (int nt = 0; nt < 4; ++nt) {
      const int nl = (nt << 4) + (lane & 15);
      short8 bF0 = *(short8*)&Bs[nl][kq];
      short8 bF1 = *(short8*)&Bs[nl][kq + 32];
      acc[nt] = __builtin_amdgcn_mfma_f32_16x16x32_bf16(aF0, bF0, acc[nt], 0, 0, 0);
      acc[nt] = __builtin_amdgcn_mfma_f32_16x16x32_bf16(aF1, bF1, acc[nt], 0, 0, 0);
    }
  }
  const int lane15 = lane & 15;
  const int rowbase = m0 + (w << 4) + ((lane >> 4) << 2);
  if (n0 < 768) {
    // q or k head: fused RMS-norm over the 64-wide head (= this n-tile)
#pragma unroll
    for (int r = 0; r < 4; ++r) {
      float ss = 0.0f;
#pragma unroll
      for (int nt = 0; nt < 4; ++nt) ss = fmaf(acc[nt][r], acc[nt][r], ss);
#pragma unroll
      for (int off = 1; off < 16; off <<= 1) ss += __shfl_xor(ss, off, 64);
      float sc2 = 8.0f * rsqrtf(ss + 1e-6f);
      const int row = rowbase + r;
      if (n0 < 512) {
        const int h = n0 >> 6;
        const float sc3 = sc2 * 0.125f;   // fold sm_scale into q
#pragma unroll
        for (int nt = 0; nt < 4; ++nt) {
          __fp16 hv = (__fp16)(acc[nt][r] * sc3);
          qh[(row * Hh + h) * Dd + (nt << 4) + lane15] = *(unsigned short*)&hv;
        }
      } else {
        const int hkv = (n0 - 512) >> 6;
#pragma unroll
        for (int nt = 0; nt < 4; ++nt) {
          __fp16 hv = (__fp16)(acc[nt][r] * sc2);
          kh[(row * HKV + hkv) * Dd + (nt << 4) + lane15] = *(unsigned short*)&hv;
        }
      }
    }
  } else {
    // v transposed: vT[((b*HKV+hkv)*64 + d)*512 + t], 4 consecutive t per store
    const int hkv = (n0 - 768) >> 6;
    const int bb = rowbase >> 9;       // batch (64-row tile is within one b)
    const int trow = rowbase & 511;
#pragma unroll
    for (int nt = 0; nt < 4; ++nt) {
      const int d = (nt << 4) + lane15;
      unsigned u0 = h2u(__builtin_amdgcn_cvt_pkrtz(acc[nt][0], acc[nt][1]));
      unsigned u1 = h2u(__builtin_amdgcn_cvt_pkrtz(acc[nt][2], acc[nt][3]));
      *(uint2*)&vT[((bb * HKV + hkv) * 64 + d) * 512 + trow] = make_uint2(u0, u1);
    }
  }
}

// ---------------- Proj MFMA GEMM: 64x64 tile, padded LDS ----------------
__global__ __launch_bounds__(256) void proj_mfma(
    const unsigned short* __restrict__ yb, const unsigned short* __restrict__ Wt,
    float* __restrict__ out) {
  __shared__ unsigned short As[64][72];
  __shared__ unsigned short Bs[64][72];
  const int m0 = blockIdx.x * 64;
  const int n0 = blockIdx.y * 64;
  const int t = threadIdx.x;
  const int w = t >> 6, lane = t & 63;
  const int srow = t >> 2, sc = (t & 3) << 4;
  float4v acc[4] = {{0,0,0,0},{0,0,0,0},{0,0,0,0},{0,0,0,0}};
  for (int k0 = 0; k0 < 512; k0 += 64) {
    uint4 a0 = *(const uint4*)&yb[(m0 + srow) * 512 + k0 + sc];
    uint4 a1 = *(const uint4*)&yb[(m0 + srow) * 512 + k0 + sc + 8];
    uint4 b0 = *(const uint4*)&Wt[(n0 + srow) * 512 + k0 + sc];
    uint4 b1 = *(const uint4*)&Wt[(n0 + srow) * 512 + k0 + sc + 8];
    __syncthreads();
    *(uint4*)&As[srow][sc] = a0; *(uint4*)&As[srow][sc + 8] = a1;
    *(uint4*)&Bs[srow][sc] = b0; *(uint4*)&Bs[srow][sc + 8] = b1;
    __syncthreads();
    const int ml = (w << 4) + (lane & 15);
    const int kq = (lane >> 4) << 3;
    short8 aF0 = *(short8*)&As[ml][kq];
    short8 aF1 = *(short8*)&As[ml][kq + 32];
#pragma unroll
    for (int nt = 0; nt < 4; ++nt) {
      const int nl = (nt << 4) + (lane & 15);
      short8 bF0 = *(short8*)&Bs[nl][kq];
      short8 bF1 = *(short8*)&Bs[nl][kq + 32];
      acc[nt] = __builtin_amdgcn_mfma_f32_16x16x32_bf16(aF0, bF0, acc[nt], 0, 0, 0);
      acc[nt] = __builtin_amdgcn_mfma_f32_16x16x32_bf16(aF1, bF1, acc[nt], 0, 0, 0);
    }
  }
#pragma unroll
  for (int nt = 0; nt < 4; ++nt) {
    int col = n0 + (nt << 4) + (lane & 15);
#pragma unroll
    for (int r = 0; r < 4; ++r) {
      int row = m0 + (w << 4) + ((lane >> 4) << 2) + r;
      out[row * 512 + col] = acc[nt][r];
    }
  }
}

// ---------------- Attention v14: v9 structure + j-split for occupancy ----------------
// v9: grid 1024 = exactly 4 blk/CU (grid-capped); VALU ~52%, LDS pipe ~45%, both
// starved of waves. VGPR=56 supports 8 waves/SIMD. Fixed-shift softmax => j-partials
// ADD exactly (no rescale). v14 splits the 8 heaviest i-tiles (i0>=256) into two
// j-chunks -> 1536 blocks = 6 blk/CU = 24 waves/CU. Split chunks write fp32 O/l
// partials (O into d_out, dead until proj; l into dead Wtq region); merge kernel
// combines. Chunk table ordered work-descending (v13 lesson: order IS the schedule).
__global__ __launch_bounds__(256, 8) void attn(
    const unsigned short* __restrict__ qh, const unsigned short* __restrict__ kh,
    const unsigned short* __restrict__ vT, const unsigned short* __restrict__ Pwh,
    unsigned short* __restrict__ yb, float* __restrict__ opart,
    float* __restrict__ lpart) {
  __shared__ __fp16 PwS[96][72];
  __shared__ __fp16 pS[32][72];   // padded: A-frag start bank = 4*(i+joct) -> 2-way
  __shared__ float lS[32];

  const int t = threadIdx.x;
  const int lane = t & 63;
  const int wu = __builtin_amdgcn_readfirstlane(t >> 6);
  const int bh = blockIdx.x;
  const int b = bh >> 3;
  const int h = bh & 7;
  const int hkv = h >> 1;
  const unsigned ae = ATAB[blockIdx.y];
  const int yp  = ae & 255;          // i0/32
  const int jts = (ae >> 8) & 255;   // first j-tile of this chunk
  const int njt = (ae >> 16) & 255;  // number of j-tiles
  const int i0 = yp << 5;

  float l_lane[8];
#pragma unroll
  for (int r = 0; r < 8; ++r) l_lane[r] = 0.0f;
  float4v oacc[2] = {{0, 0, 0, 0}, {0, 0, 0, 0}};

  const int prow = (wu << 3) + 63 - lane;
  const int i_base = i0 + (wu << 3);
  const unsigned short* qbase = &qh[((b * Tt + i_base) * Hh + h) * Dd];

  // PV fragment roles
  const int i16 = (wu & 1) << 4;        // A-operand i-tile base row in pS
  const int dt0 = (wu >> 1) << 1;       // first of 2 d-tiles
  const int lm = lane & 15;
  const int kq = (lane >> 4) << 3;      // k (j) octet within 32-half
  const unsigned short* vTbase = &vT[((b * HKV + hkv) * 64) * 512];

  for (int jt = jts; jt < jts + njt; ++jt) {
    const int jt0 = jt << 6;
    __syncthreads();   // guards PwS restage + pS rewrite vs prior PV reads
    {
      int jr = t >> 2, dc = (t & 3) << 4;
      const int pb0 = h * 1023 + (i0 - jt0) + 448;
      const unsigned short* pwp = &Pwh[(pb0 + jr) * 64 + dc];
      *(uint4*)&PwS[jr][dc]     = *(const uint4*)&pwp[0];
      *(uint4*)&PwS[jr][dc + 8] = *(const uint4*)&pwp[8];
      int pr2 = 64 + (t >> 3), dc2 = (t & 7) << 3;
      if (pr2 < 95)
        *(uint4*)&PwS[pr2][dc2] = *(const uint4*)&Pwh[(pb0 + pr2) * 64 + dc2];
    }
    uint4 kr[8];
    {
      const uint4* kp = (const uint4*)&kh[((b * Tt + jt0 + lane) * HKV + hkv) * Dd];
#pragma unroll
      for (int c = 0; c < 8; ++c) kr[c] = kp[c];
    }
    __syncthreads();   // PwS ready

    // ---- score phase: lane = j; q broadcast from global, Pw from LDS, K regs ----
    const int j = jt0 + lane;
#pragma unroll
    for (int r = 0; r < 8; ++r) {
      const uint4* qp = (const uint4*)&qbase[r * (Hh * Dd)];  // wave-uniform
      float srx = 0.0f, sry = 0.0f, srz = 0.0f, srw = 0.0f;
#pragma unroll
      for (int ch = 0; ch < 8; ++ch) {
        uint4 qu = qp[ch];
        uint4 pu = *(uint4*)&PwS[prow + r][ch << 3];
        srx = fdot2(u2h(qu.x) * u2h(pu.x), u2h(kr[ch].x), srx);
        sry = fdot2(u2h(qu.y) * u2h(pu.y), u2h(kr[ch].y), sry);
        srz = fdot2(u2h(qu.z) * u2h(pu.z), u2h(kr[ch].z), srz);
        srw = fdot2(u2h(qu.w) * u2h(pu.w), u2h(kr[ch].w), srw);
      }
      float sr = (srx + sry) + (srz + srw);
      float sv = (j <= i_base + r) ? sr : -1e30f;   // sm_scale pre-folded in qh
      float p = __expf(sv - 6.0f);   // fixed shift: exact softmax, partials add
      l_lane[r] += p;
      pS[(wu << 3) + r][lane] = (__fp16)p;   // b16 store, 2-way banks
    }
    __syncthreads();   // pS ready for all waves

    // ---- PV phase: MFMA f16, A from pS, B from vT (global, L1/L2-hot) ----
    half8 a0 = *(half8*)&pS[i16 + lm][kq];
    half8 a1 = *(half8*)&pS[i16 + lm][kq + 32];
#pragma unroll
    for (int dd = 0; dd < 2; ++dd) {
      const unsigned short* vp = vTbase + (((dt0 + dd) << 4) + lm) * 512 + jt0 + kq;
      half8 b0 = *(const half8*)&vp[0];
      half8 b1 = *(const half8*)&vp[32];
      oacc[dd] = __builtin_amdgcn_mfma_f32_16x16x32_f16(a0, b0, oacc[dd], 0, 0, 0);
      oacc[dd] = __builtin_amdgcn_mfma_f32_16x16x32_f16(a1, b1, oacc[dd], 0, 0, 0);
    }
  }

  // final l reduction (once), shared via lS (score rows != C-layout rows)
#pragma unroll
  for (int r = 0; r < 8; ++r) {
    float lr = wave_reduce_sum(l_lane[r]);
    if (lane == r) lS[(wu << 3) + r] = lr;
  }
  __syncthreads();

  if (yp >= 8) {
    // split tile: write fp32 partials; merge kernel combines the two chunks
    const int slot = (jts != 0);
    const int pbase = (((bh << 3) + (yp - 8)) << 1) + slot;
    float* ob = opart + pbase * 2048;
#pragma unroll
    for (int dd = 0; dd < 2; ++dd) {
      const int d = ((dt0 + dd) << 4) + lm;
#pragma unroll
      for (int r = 0; r < 4; ++r) {
        const int irow = i16 + ((lane >> 4) << 2) + r;
        ob[irow * 64 + d] = oacc[dd][r];
      }
    }
    if (t < 32) lpart[pbase * 32 + t] = lS[t];
  } else {
    // unsplit: divide and store bf16 as before
#pragma unroll
    for (int dd = 0; dd < 2; ++dd) {
      const int d = ((dt0 + dd) << 4) + lm;
#pragma unroll
      for (int r = 0; r < 4; ++r) {
        const int irow = i16 + ((lane >> 4) << 2) + r;
        const float val = oacc[dd][r] / lS[irow];
        __hip_bfloat16 hv = __float2bfloat16(val);
        yb[((b * Tt + i0 + irow) * Hh + h) * Dd + d] = *(unsigned short*)&hv;
      }
    }
  }
}

// ---------------- merge: yb = (O_A + O_B) / (l_A + l_B) for split tiles ----------------
__global__ __launch_bounds__(256) void merge(
    const float* __restrict__ opart, const float* __restrict__ lpart,
    unsigned short* __restrict__ yb) {
  const int bt = blockIdx.x;        // bh*8 + (yp-8)
  const int bh = bt >> 3;
  const int b = bh >> 3, h = bh & 7;
  const int i0 = ((bt & 7) + 8) << 5;
  const int t = threadIdx.x;
  const int row = t >> 3;           // 0..31
  const int d0 = (t & 7) << 3;      // 0..56 step 8
  const float* oA = opart + (bt << 1) * 2048;
  const float* oB = oA + 2048;
  const float linv = 1.0f / (lpart[(bt << 1) * 32 + row] + lpart[((bt << 1) + 1) * 32 + row]);
  float4 a0 = *(const float4*)&oA[row * 64 + d0];
  float4 a1 = *(const float4*)&oA[row * 64 + d0 + 4];
  float4 b0 = *(const float4*)&oB[row * 64 + d0];
  float4 b1 = *(const float4*)&oB[row * 64 + d0 + 4];
  unsigned u[4];
  u[0] = pack_bf2((a0.x + b0.x) * linv, (a0.y + b0.y) * linv);
  u[1] = pack_bf2((a0.z + b0.z) * linv, (a0.w + b0.w) * linv);
  u[2] = pack_bf2((a1.x + b1.x) * linv, (a1.y + b1.y) * linv);
  u[3] = pack_bf2((a1.z + b1.z) * linv, (a1.w + b1.w) * linv);
  *(uint4*)&yb[((b * Tt + i0 + row) * Hh + h) * Dd + d0] = *(uint4*)u;
}

extern "C" void kernel_launch(void* const* d_in, const int* in_sizes, int n_in,
                              void* d_out, int out_size, void* d_ws, size_t ws_size,
                              hipStream_t stream) {
  const float* x     = (const float*)d_in[0];
  const float* Wq    = (const float*)d_in[1];
  const float* Wk    = (const float*)d_in[2];
  const float* Wv    = (const float*)d_in[3];
  const float* Wproj = (const float*)d_in[4];
  const float* P     = (const float*)d_in[5];
  const float* sigma = (const float*)d_in[6];
  float* out = (float*)d_out;

  float* ws = (float*)d_ws;
  unsigned short* qh  = (unsigned short*)ws;                // 2,097,152 h = 1,048,576 f
  unsigned short* kh  = (unsigned short*)(ws + 1048576);    // 1,048,576 h = 524,288 f
  unsigned short* vT  = (unsigned short*)(ws + 1572864);    // 1,048,576 h = 524,288 f (transposed)
  unsigned short* Pwh = (unsigned short*)(ws + 2097152);    // 523,776 h -> 262,144 f
  unsigned short* xb  = (unsigned short*)(ws + 2359296);    // 2M bf16 = 1,048,576 f
  unsigned short* yb  = xb;                                 // alias: xb dead after qkv_mfma
  unsigned short* Wtq = (unsigned short*)(ws + 3407872);    // 524,288 h = 262,144 f
  unsigned short* Wtp = (unsigned short*)(ws + 3670016);    // 262,144 h = 131,072 f

  // v14 partial buffers: O partials use d_out (dead until proj, exactly 2M floats);
  // l partials use the Wtq region (dead after qkv_mfma; needs 32K floats).
  float* opart = out;
  float* lpart = ws + 3407872;

  prep<<<dim3(3262), 256, 0, stream>>>(x, Wq, Wk, Wv, Wproj, P, sigma,
                                       xb, Wtq, Wtp, Pwh);
  qkv_mfma<<<dim3(64, 16), 256, 0, stream>>>(xb, Wtq, qh, kh, vT);
  attn<<<dim3(64, 24), 256, 0, stream>>>(qh, kh, vT, Pwh, yb, opart, lpart);
  merge<<<dim3(512), 256, 0, stream>>>(opart, lpart, yb);
  proj_mfma<<<dim3(64, 8), 256, 0, stream>>>(yb, Wtp, out);
}

// Round 8
// 147.105 us; speedup vs baseline: 1.1192x; 1.1192x over previous
//
#include <hip/hip_runtime.h>
#include <hip/hip_bf16.h>
#include <math.h>

#define Bb 8
#define Tt 512
#define Cc 512
#define Hh 8
#define HKV 4
#define Dd 64

typedef __attribute__((ext_vector_type(8))) short short8;
typedef __attribute__((ext_vector_type(4))) float float4v;
typedef __attribute__((ext_vector_type(2))) __fp16 h2;   // matches cvt_pkrtz return
typedef __attribute__((ext_vector_type(8))) __fp16 half8; // f16 MFMA fragment

__device__ __forceinline__ h2 u2h(unsigned u) {
  union { unsigned u; h2 h; } x; x.u = u; return x.h;
}
__device__ __forceinline__ unsigned h2u(h2 h) {
  union { h2 h; unsigned u; } x; x.h = h; return x.u;
}
__device__ __forceinline__ float fdot2(h2 a, h2 b, float c) {
#if __has_builtin(__builtin_amdgcn_fdot2)
  return __builtin_amdgcn_fdot2(a, b, c, false);
#else
  return fmaf((float)a.x, (float)b.x, fmaf((float)a.y, (float)b.y, c));
#endif
}

__device__ __forceinline__ float wave_reduce_sum(float v) {
#pragma unroll
  for (int off = 32; off > 0; off >>= 1) v += __shfl_xor(v, off, 64);
  return v;
}
__device__ __forceinline__ unsigned pack_bf2(float a, float b) {
  __hip_bfloat162 h = __float22bfloat162_rn(make_float2(a, b));
  return *(unsigned*)&h;
}

// v15 attn chunk table: (yp | jts<<8 | njt<<16), roughly descending work.
// yp = i0/32; tiles yp>=8 split into two j-chunks (fixed-shift softmax => partials add).
// Co-resident sets {y, y+4, ..., y+20} (6 blocks/CU) each sum 18 iter-units.
__constant__ unsigned ATAB[24] = {
  0x04000F, 0x04000E, 0x04040F, 0x04040E, 0x04000D, 0x04000C,  // njt4 chunks
  0x03040D, 0x03040C, 0x03000B, 0x03000A, 0x03030B, 0x03030A,  // njt3 chunks
  0x030009, 0x030008,                                           // njt3 chunks
  0x040007, 0x040006,                                           // unsplit nt4
  0x020309, 0x020308,                                           // njt2 tails
  0x030005, 0x030004,                                           // unsplit nt3
  0x020003, 0x020002,                                           // unsplit nt2
  0x010001, 0x010000                                            // unsplit nt1
};

// ---------------- fused prep: conv_x | conv_w | build_pw (by block range) ----------------
__global__ __launch_bounds__(256) void prep(
    const float* __restrict__ x, const float* __restrict__ Wq,
    const float* __restrict__ Wk, const float* __restrict__ Wv,
    const float* __restrict__ Wp, const float* __restrict__ P,
    const float* __restrict__ sigma,
    unsigned short* __restrict__ xb, unsigned short* __restrict__ Wtq,
    unsigned short* __restrict__ Wtp, unsigned short* __restrict__ Pwh) {
  const int bid = blockIdx.x;
  const int t = threadIdx.x;
  if (bid < 1024) {
    int i = (bid * 256 + t) * 8;
    float4 f0 = *(const float4*)&x[i];
    float4 f1 = *(const float4*)&x[i + 4];
    unsigned u[4] = {pack_bf2(f0.x, f0.y), pack_bf2(f0.z, f0.w),
                     pack_bf2(f1.x, f1.y), pack_bf2(f1.z, f1.w)};
    *(uint4*)&xb[i] = *(uint4*)u;
  } else if (bid < 1216) {
    __shared__ float Ts[64][65];
    const int bx = bid - 1024;
    const int k0 = (bx & 7) << 6;
    const int n0 = (bx >> 3) << 6;
    const float* src; int ld, nc0; unsigned short* dst; int ndst;
    if (n0 < 512)       { src = Wq; ld = 512; nc0 = n0;        dst = Wtq; ndst = n0; }
    else if (n0 < 768)  { src = Wk; ld = 256; nc0 = n0 - 512;  dst = Wtq; ndst = n0; }
    else if (n0 < 1024) { src = Wv; ld = 256; nc0 = n0 - 768;  dst = Wtq; ndst = n0; }
    else                { src = Wp; ld = 512; nc0 = n0 - 1024; dst = Wtp; ndst = n0 - 1024; }
    const int r = t >> 4, c4 = (t & 15) << 2;
#pragma unroll
    for (int rr = 0; rr < 4; ++rr) {
      int row = (rr << 4) + r;
      float4 f = *(const float4*)&src[(k0 + row) * ld + nc0 + c4];
      Ts[row][c4] = f.x; Ts[row][c4 + 1] = f.y;
      Ts[row][c4 + 2] = f.z; Ts[row][c4 + 3] = f.w;
    }
    __syncthreads();
#pragma unroll
    for (int rr = 0; rr < 4; ++rr) {
      int nr = (rr << 4) + r;
      unsigned u0 = pack_bf2(Ts[c4][nr], Ts[c4 + 1][nr]);
      unsigned u1 = pack_bf2(Ts[c4 + 2][nr], Ts[c4 + 3][nr]);
      *(uint2*)&dst[(ndst + nr) * 512 + k0 + c4] = make_uint2(u0, u1);
    }
  } else {
    int idx = (bid - 1216) * 256 + t;
    int d = idx & 63;
    int rem = idx >> 6;
    int dd = rem % 1023;
    int h = rem / 1023;
    float s = fabsf(sigma[h]) + 1e-6f;
    float delta = (float)(dd - 511);
    float dt = 128.0f * tanhf(delta / s) + 128.0f;
    float lo = floorf(dt);
    int ilo = (int)lo;
    float frac = dt - lo;
    ilo = max(0, min(ilo, 256));
    int ihi = min(ilo + 1, 256);
    const float* Pb = P + h * 257 * 64;
    float val = (1.0f - frac) * Pb[ilo * 64 + d] + frac * Pb[ihi * 64 + d];
    __fp16 hv = (__fp16)val;
    Pwh[idx] = *(unsigned short*)&hv;
  }
}

// ---------------- QKV MFMA GEMM: 64x64 tile, padded LDS; v emitted TRANSPOSED ----------------
// sm_scale (1/8) folded into the q store -> attn drops its per-score multiply.
__global__ __launch_bounds__(256) void qkv_mfma(
    const unsigned short* __restrict__ xb, const unsigned short* __restrict__ Wt,
    unsigned short* __restrict__ qh, unsigned short* __restrict__ kh,
    unsigned short* __restrict__ vT) {
  __shared__ unsigned short As[64][72];
  __shared__ unsigned short Bs[64][72];
  const int m0 = blockIdx.x * 64;
  const int n0 = blockIdx.y * 64;
  const int t = threadIdx.x;
  const int w = t >> 6, lane = t & 63;
  const int srow = t >> 2, sc = (t & 3) << 4;
  float4v acc[4] = {{0,0,0,0},{0,0,0,0},{0,0,0,0},{0,0,0,0}};
  for (int k0 = 0; k0 < 512; k0 += 64) {
    uint4 a0 = *(const uint4*)&xb[(m0 + srow) * 512 + k0 + sc];
    uint4 a1 = *(const uint4*)&xb[(m0 + srow) * 512 + k0 + sc + 8];
    uint4 b0 = *(const uint4*)&Wt[(n0 + srow) * 512 + k0 + sc];
    uint4 b1 = *(const uint4*)&Wt[(n0 + srow) * 512 + k0 + sc + 8];
    __syncthreads();
    *(uint4*)&As[srow][sc] = a0; *(uint4*)&As[srow][sc + 8] = a1;
    *(uint4*)&Bs[srow][sc] = b0; *(uint4*)&Bs[srow][sc + 8] = b1;
    __syncthreads();
    const int ml = (w << 4) + (lane & 15);
    const int kq = (lane >> 4) << 3;
    short8 aF0 = *(short8*)&As[ml][kq];
    short8 aF1 = *(short8*)&As[ml][kq + 32];
#pragma unroll
    for (int nt = 0; nt < 4; ++nt) {
      const int nl = (nt << 4) + (lane & 15);
      short8 bF0 = *(short8*)&Bs[nl][kq];
      short8 bF1 = *(short8*)&Bs[nl][kq + 32];
      acc[nt] = __builtin_amdgcn_mfma_f32_16x16x32_bf16(aF0, bF0, acc[nt], 0, 0, 0);
      acc[nt] = __builtin_amdgcn_mfma_f32_16x16x32_bf16(aF1, bF1, acc[nt], 0, 0, 0);
    }
  }
  const int lane15 = lane & 15;
  const int rowbase = m0 + (w << 4) + ((lane >> 4) << 2);
  if (n0 < 768) {
    // q or k head: fused RMS-norm over the 64-wide head (= this n-tile)
#pragma unroll
    for (int r = 0; r < 4; ++r) {
      float ss = 0.0f;
#pragma unroll
      for (int nt = 0; nt < 4; ++nt) ss = fmaf(acc[nt][r], acc[nt][r], ss);
#pragma unroll
      for (int off = 1; off < 16; off <<= 1) ss += __shfl_xor(ss, off, 64);
      float sc2 = 8.0f * rsqrtf(ss + 1e-6f);
      const int row = rowbase + r;
      if (n0 < 512) {
        const int h = n0 >> 6;
        const float sc3 = sc2 * 0.125f;   // fold sm_scale into q
#pragma unroll
        for (int nt = 0; nt < 4; ++nt) {
          __fp16 hv = (__fp16)(acc[nt][r] * sc3);
          qh[(row * Hh + h) * Dd + (nt << 4) + lane15] = *(unsigned short*)&hv;
        }
      } else {
        const int hkv = (n0 - 512) >> 6;
#pragma unroll
        for (int nt = 0; nt < 4; ++nt) {
          __fp16 hv = (__fp16)(acc[nt][r] * sc2);
          kh[(row * HKV + hkv) * Dd + (nt << 4) + lane15] = *(unsigned short*)&hv;
        }
      }
    }
  } else {
    // v transposed: vT[((b*HKV+hkv)*64 + d)*512 + t], 4 consecutive t per store
    const int hkv = (n0 - 768) >> 6;
    const int bb = rowbase >> 9;       // batch (64-row tile is within one b)
    const int trow = rowbase & 511;
#pragma unroll
    for (int nt = 0; nt < 4; ++nt) {
      const int d = (nt << 4) + lane15;
      unsigned u0 = h2u(__builtin_amdgcn_cvt_pkrtz(acc[nt][0], acc[nt][1]));
      unsigned u1 = h2u(__builtin_amdgcn_cvt_pkrtz(acc[nt][2], acc[nt][3]));
      *(uint2*)&vT[((bb * HKV + hkv) * 64 + d) * 512 + trow] = make_uint2(u0, u1);
    }
  }
}

// ---------------- Proj MFMA GEMM: 64x64 tile, padded LDS ----------------
__global__ __launch_bounds__(256) void proj_mfma(
    const unsigned short* __restrict__ yb, const unsigned short* __restrict__ Wt,
    float* __restrict__ out) {
  __shared__ unsigned short As[64][72];
  __shared__ unsigned short Bs[64][72];
  const int m0 = blockIdx.x * 64;
  const int n0 = blockIdx.y * 64;
  const int t = threadIdx.x;
  const int w = t >> 6, lane = t & 63;
  const int srow = t >> 2, sc = (t & 3) << 4;
  float4v acc[4] = {{0,0,0,0},{0,0,0,0},{0,0,0,0},{0,0,0,0}};
  for (int k0 = 0; k0 < 512; k0 += 64) {
    uint4 a0 = *(const uint4*)&yb[(m0 + srow) * 512 + k0 + sc];
    uint4 a1 = *(const uint4*)&yb[(m0 + srow) * 512 + k0 + sc + 8];
    uint4 b0 = *(const uint4*)&Wt[(n0 + srow) * 512 + k0 + sc];
    uint4 b1 = *(const uint4*)&Wt[(n0 + srow) * 512 + k0 + sc + 8];
    __syncthreads();
    *(uint4*)&As[srow][sc] = a0; *(uint4*)&As[srow][sc + 8] = a1;
    *(uint4*)&Bs[srow][sc] = b0; *(uint4*)&Bs[srow][sc + 8] = b1;
    __syncthreads();
    const int ml = (w << 4) + (lane & 15);
    const int kq = (lane >> 4) << 3;
    short8 aF0 = *(short8*)&As[ml][kq];
    short8 aF1 = *(short8*)&As[ml][kq + 32];
#pragma unroll
    for (int nt = 0; nt < 4; ++nt) {
      const int nl = (nt << 4) + (lane & 15);
      short8 bF0 = *(short8*)&Bs[nl][kq];
      short8 bF1 = *(short8*)&Bs[nl][kq + 32];
      acc[nt] = __builtin_amdgcn_mfma_f32_16x16x32_bf16(aF0, bF0, acc[nt], 0, 0, 0);
      acc[nt] = __builtin_amdgcn_mfma_f32_16x16x32_bf16(aF1, bF1, acc[nt], 0, 0, 0);
    }
  }
#pragma unroll
  for (int nt = 0; nt < 4; ++nt) {
    int col = n0 + (nt << 4) + (lane & 15);
#pragma unroll
    for (int r = 0; r < 4; ++r) {
      int row = m0 + (w << 4) + ((lane >> 4) << 2) + r;
      out[row * 512 + col] = acc[nt][r];
    }
  }
}

// ---------------- Attention v15: v9 inner loop + j-split, NO register cap ----------------
// v14 failed on __launch_bounds__(256,8): VGPR forced 32 -> spill storm (W 139MB).
// Rule: never use the 2nd launch_bounds arg. v13 lesson: single-chain fdot2 beats
// 4-way split. v15 = v9 body exactly + j-split chunk table: 1536 blocks = 6 blk/CU
// = 24 waves/CU (LDS 6x18.9K=114K fits; VGPR ~56-64 x 24 waves <= 2048 fits).
// Split chunks write fp32 O/l partials; fixed-shift softmax => partials ADD exactly.
__global__ __launch_bounds__(256) void attn(
    const unsigned short* __restrict__ qh, const unsigned short* __restrict__ kh,
    const unsigned short* __restrict__ vT, const unsigned short* __restrict__ Pwh,
    unsigned short* __restrict__ yb, float* __restrict__ opart,
    float* __restrict__ lpart) {
  __shared__ __fp16 PwS[96][72];
  __shared__ __fp16 pS[32][72];   // padded: A-frag start bank = 4*(i+joct) -> 2-way
  __shared__ float lS[32];

  const int t = threadIdx.x;
  const int lane = t & 63;
  const int wu = __builtin_amdgcn_readfirstlane(t >> 6);
  const int bh = blockIdx.x;
  const int b = bh >> 3;
  const int h = bh & 7;
  const int hkv = h >> 1;
  const unsigned ae = ATAB[blockIdx.y];
  const int yp  = ae & 255;          // i0/32
  const int jts = (ae >> 8) & 255;   // first j-tile of this chunk
  const int njt = (ae >> 16) & 255;  // number of j-tiles
  const int i0 = yp << 5;

  float l_lane[8];
#pragma unroll
  for (int r = 0; r < 8; ++r) l_lane[r] = 0.0f;
  float4v oacc[2] = {{0, 0, 0, 0}, {0, 0, 0, 0}};

  const int prow = (wu << 3) + 63 - lane;
  const int i_base = i0 + (wu << 3);
  const unsigned short* qbase = &qh[((b * Tt + i_base) * Hh + h) * Dd];

  // PV fragment roles
  const int i16 = (wu & 1) << 4;        // A-operand i-tile base row in pS
  const int dt0 = (wu >> 1) << 1;       // first of 2 d-tiles
  const int lm = lane & 15;
  const int kq = (lane >> 4) << 3;      // k (j) octet within 32-half
  const unsigned short* vTbase = &vT[((b * HKV + hkv) * 64) * 512];

  for (int jt = jts; jt < jts + njt; ++jt) {
    const int jt0 = jt << 6;
    __syncthreads();   // guards PwS restage + pS rewrite vs prior PV reads
    {
      int jr = t >> 2, dc = (t & 3) << 4;
      const int pb0 = h * 1023 + (i0 - jt0) + 448;
      const unsigned short* pwp = &Pwh[(pb0 + jr) * 64 + dc];
      *(uint4*)&PwS[jr][dc]     = *(const uint4*)&pwp[0];
      *(uint4*)&PwS[jr][dc + 8] = *(const uint4*)&pwp[8];
      int pr2 = 64 + (t >> 3), dc2 = (t & 7) << 3;
      if (pr2 < 95)
        *(uint4*)&PwS[pr2][dc2] = *(const uint4*)&Pwh[(pb0 + pr2) * 64 + dc2];
    }
    uint4 kr[8];
    {
      const uint4* kp = (const uint4*)&kh[((b * Tt + jt0 + lane) * HKV + hkv) * Dd];
#pragma unroll
      for (int c = 0; c < 8; ++c) kr[c] = kp[c];
    }
    __syncthreads();   // PwS ready

    // ---- score phase: lane = j; q broadcast from global, Pw from LDS, K regs ----
    const int j = jt0 + lane;
#pragma unroll
    for (int r = 0; r < 8; ++r) {
      const uint4* qp = (const uint4*)&qbase[r * (Hh * Dd)];  // wave-uniform
      float sr = 0.0f;
#pragma unroll
      for (int ch = 0; ch < 8; ++ch) {
        uint4 qu = qp[ch];
        uint4 pu = *(uint4*)&PwS[prow + r][ch << 3];
        sr = fdot2(u2h(qu.x) * u2h(pu.x), u2h(kr[ch].x), sr);
        sr = fdot2(u2h(qu.y) * u2h(pu.y), u2h(kr[ch].y), sr);
        sr = fdot2(u2h(qu.z) * u2h(pu.z), u2h(kr[ch].z), sr);
        sr = fdot2(u2h(qu.w) * u2h(pu.w), u2h(kr[ch].w), sr);
      }
      float sv = (j <= i_base + r) ? sr : -1e30f;   // sm_scale pre-folded in qh
      float p = __expf(sv - 6.0f);   // fixed shift: exact softmax, partials add
      l_lane[r] += p;
      pS[(wu << 3) + r][lane] = (__fp16)p;   // b16 store, 2-way banks
    }
    __syncthreads();   // pS ready for all waves

    // ---- PV phase: MFMA f16, A from pS, B from vT (global, L1/L2-hot) ----
    half8 a0 = *(half8*)&pS[i16 + lm][kq];
    half8 a1 = *(half8*)&pS[i16 + lm][kq + 32];
#pragma unroll
    for (int dd = 0; dd < 2; ++dd) {
      const unsigned short* vp = vTbase + (((dt0 + dd) << 4) + lm) * 512 + jt0 + kq;
      half8 b0 = *(const half8*)&vp[0];
      half8 b1 = *(const half8*)&vp[32];
      oacc[dd] = __builtin_amdgcn_mfma_f32_16x16x32_f16(a0, b0, oacc[dd], 0, 0, 0);
      oacc[dd] = __builtin_amdgcn_mfma_f32_16x16x32_f16(a1, b1, oacc[dd], 0, 0, 0);
    }
  }

  // final l reduction (once), shared via lS (score rows != C-layout rows)
#pragma unroll
  for (int r = 0; r < 8; ++r) {
    float lr = wave_reduce_sum(l_lane[r]);
    if (lane == r) lS[(wu << 3) + r] = lr;
  }
  __syncthreads();

  if (yp >= 8) {
    // split tile: write fp32 partials; merge kernel combines the two chunks
    const int slot = (jts != 0);
    const int pbase = (((bh << 3) + (yp - 8)) << 1) + slot;
    float* ob = opart + pbase * 2048;
#pragma unroll
    for (int dd = 0; dd < 2; ++dd) {
      const int d = ((dt0 + dd) << 4) + lm;
#pragma unroll
      for (int r = 0; r < 4; ++r) {
        const int irow = i16 + ((lane >> 4) << 2) + r;
        ob[irow * 64 + d] = oacc[dd][r];
      }
    }
    if (t < 32) lpart[pbase * 32 + t] = lS[t];
  } else {
    // unsplit: divide and store bf16 as before
#pragma unroll
    for (int dd = 0; dd < 2; ++dd) {
      const int d = ((dt0 + dd) << 4) + lm;
#pragma unroll
      for (int r = 0; r < 4; ++r) {
        const int irow = i16 + ((lane >> 4) << 2) + r;
        const float val = oacc[dd][r] / lS[irow];
        __hip_bfloat16 hv = __float2bfloat16(val);
        yb[((b * Tt + i0 + irow) * Hh + h) * Dd + d] = *(unsigned short*)&hv;
      }
    }
  }
}

// ---------------- merge: yb = (O_A + O_B) / (l_A + l_B) for split tiles ----------------
__global__ __launch_bounds__(256) void merge(
    const float* __restrict__ opart, const float* __restrict__ lpart,
    unsigned short* __restrict__ yb) {
  const int bt = blockIdx.x;        // bh*8 + (yp-8)
  const int bh = bt >> 3;
  const int b = bh >> 3, h = bh & 7;
  const int i0 = ((bt & 7) + 8) << 5;
  const int t = threadIdx.x;
  const int row = t >> 3;           // 0..31
  const int d0 = (t & 7) << 3;      // 0..56 step 8
  const float* oA = opart + (bt << 1) * 2048;
  const float* oB = oA + 2048;
  const float linv = 1.0f / (lpart[(bt << 1) * 32 + row] + lpart[((bt << 1) + 1) * 32 + row]);
  float4 a0 = *(const float4*)&oA[row * 64 + d0];
  float4 a1 = *(const float4*)&oA[row * 64 + d0 + 4];
  float4 b0 = *(const float4*)&oB[row * 64 + d0];
  float4 b1 = *(const float4*)&oB[row * 64 + d0 + 4];
  unsigned u[4];
  u[0] = pack_bf2((a0.x + b0.x) * linv, (a0.y + b0.y) * linv);
  u[1] = pack_bf2((a0.z + b0.z) * linv, (a0.w + b0.w) * linv);
  u[2] = pack_bf2((a1.x + b1.x) * linv, (a1.y + b1.y) * linv);
  u[3] = pack_bf2((a1.z + b1.z) * linv, (a1.w + b1.w) * linv);
  *(uint4*)&yb[((b * Tt + i0 + row) * Hh + h) * Dd + d0] = *(uint4*)u;
}

extern "C" void kernel_launch(void* const* d_in, const int* in_sizes, int n_in,
                              void* d_out, int out_size, void* d_ws, size_t ws_size,
                              hipStream_t stream) {
  const float* x     = (const float*)d_in[0];
  const float* Wq    = (const float*)d_in[1];
  const float* Wk    = (const float*)d_in[2];
  const float* Wv    = (const float*)d_in[3];
  const float* Wproj = (const float*)d_in[4];
  const float* P     = (const float*)d_in[5];
  const float* sigma = (const float*)d_in[6];
  float* out = (float*)d_out;

  float* ws = (float*)d_ws;
  unsigned short* qh  = (unsigned short*)ws;                // 2,097,152 h = 1,048,576 f
  unsigned short* kh  = (unsigned short*)(ws + 1048576);    // 1,048,576 h = 524,288 f
  unsigned short* vT  = (unsigned short*)(ws + 1572864);    // 1,048,576 h = 524,288 f (transposed)
  unsigned short* Pwh = (unsigned short*)(ws + 2097152);    // 523,776 h -> 262,144 f
  unsigned short* xb  = (unsigned short*)(ws + 2359296);    // 2M bf16 = 1,048,576 f
  unsigned short* yb  = xb;                                 // alias: xb dead after qkv_mfma
  unsigned short* Wtq = (unsigned short*)(ws + 3407872);    // 524,288 h = 262,144 f
  unsigned short* Wtp = (unsigned short*)(ws + 3670016);    // 262,144 h = 131,072 f

  // partial buffers: O partials use d_out (dead until proj, exactly 2M floats);
  // l partials use the Wtq region (dead after qkv_mfma; needs 32K floats).
  float* opart = out;
  float* lpart = ws + 3407872;

  prep<<<dim3(3262), 256, 0, stream>>>(x, Wq, Wk, Wv, Wproj, P, sigma,
                                       xb, Wtq, Wtp, Pwh);
  qkv_mfma<<<dim3(64, 16), 256, 0, stream>>>(xb, Wtq, qh, kh, vT);
  attn<<<dim3(64, 24), 256, 0, stream>>>(qh, kh, vT, Pwh, yb, opart, lpart);
  merge<<<dim3(512), 256, 0, stream>>>(opart, lpart, yb);
  proj_mfma<<<dim3(64, 8), 256, 0, stream>>>(yb, Wtp, out);
}